// Round 1
// baseline (601.360 us; speedup 1.0000x reference)
//
#include <hip/hip_runtime.h>
#include <stdint.h>

// Quant4-LUT matvec: y = x @ dequant(qweight, kmvalues)^T + bias
// qweight arrives as (28672, 4096) int32, one packed byte per element
// (lo nibble = even col, hi = odd). 469.8 MB stream -> HBM roofline ~75 us.
//
// v2 (this round): remove ALL __syncthreads + per-row phase serialization.
//  - All 7 per-row byte->half2 LUTs built up front (per-wave LDS slices,
//    same-wave DS ordering makes barriers unnecessary).
//  - kmv/bias preloaded for all 7 rows (no global-load latency inside loop).
//  - Half-row A/B register double buffer: row r+1's codes stream in while
//    row r's hot loop consumes, so ~8-16 KB/wave stays in flight always.

typedef _Float16 half2_t __attribute__((ext_vector_type(2)));

#define OUT_F     28672
#define ROW_ELEMS 4096                   // int32 code elements per row
#define NBLOCKS   1024
#define WPB       4                      // waves per block
#define NWAVES    (NBLOCKS * WPB)        // 4096
#define RPW       (OUT_F / NWAVES)       // 7 rows per wave, exact

__device__ __forceinline__ float dot2acc(half2_t a, half2_t b, float c) {
#if __has_builtin(__builtin_amdgcn_fdot2)
    return __builtin_amdgcn_fdot2(a, b, c, false);
#else
    return c + (float)a.x * (float)b.x + (float)a.y * (float)b.y;
#endif
}

__global__ __launch_bounds__(256) void q4lut_matvec(
    const float* __restrict__ x,
    const int*   __restrict__ qw,     // int32 per byte-code
    const float* __restrict__ kmv,
    const float* __restrict__ bias,
    float* __restrict__ out)
{
    // Per-wave, per-row pair LUTs. Each wave touches ONLY its own [wave] slice,
    // so no block barrier is ever needed (same-wave DS executes in order and
    // the compiler inserts lgkmcnt waits for the write->read dependence).
    __shared__ uint32_t pairlut[WPB][RPW][256];   // 28 KiB/block

    const int tid   = threadIdx.x;
    const int wave  = tid >> 6;
    const int lane  = tid & 63;
    const int gwave = blockIdx.x * WPB + wave;

    // ---- Preload this lane's x slice (reused by all 7 rows).
    // Code element e = c*256 + lane*4 + k covers x[2e], x[2e+1]
    // -> lane's floats per chunk c: x[c*512 + lane*8 + 0..8).
    half2_t xp[64];
#pragma unroll
    for (int c = 0; c < 16; ++c) {
        const float4* xs = reinterpret_cast<const float4*>(x + c * 512 + lane * 8);
        float4 v0 = xs[0];
        float4 v1 = xs[1];
        xp[c * 4 + 0] = half2_t{(_Float16)v0.x, (_Float16)v0.y};
        xp[c * 4 + 1] = half2_t{(_Float16)v0.z, (_Float16)v0.w};
        xp[c * 4 + 2] = half2_t{(_Float16)v1.x, (_Float16)v1.y};
        xp[c * 4 + 3] = half2_t{(_Float16)v1.z, (_Float16)v1.w};
    }

    // ---- Build ALL row LUTs + preload bias up front (off the hot path).
    // Lane holds lut[lane & 15]; entry e = lane*4 + k needs
    // lo = lut[e & 15] = shfl((lane&3)*4+k), hi = lut[e>>4] = shfl(lane>>2).
    float biasv[RPW];
#pragma unroll
    for (int r = 0; r < RPW; ++r) {
        const int row = gwave + NWAVES * r;
        const float myv = kmv[row * 16 + (lane & 15)];
        biasv[r] = bias[row];
        const _Float16 hih = (_Float16)__shfl(myv, lane >> 2, 64);
        uint32_t ent[4];
#pragma unroll
        for (int k = 0; k < 4; ++k) {
            const _Float16 loh = (_Float16)__shfl(myv, ((lane & 3) << 2) + k, 64);
            half2_t p = {loh, hih};
            ent[k] = __builtin_bit_cast(uint32_t, p);
        }
        *reinterpret_cast<uint4*>(&pairlut[wave][r][lane * 4]) =
            make_uint4(ent[0], ent[1], ent[2], ent[3]);
    }

    // ---- Software-pipelined code stream: half-row (8 KiB) double buffer.
    uint4 A[8], B[8];
    {
        const uint4* q0 =
            reinterpret_cast<const uint4*>(qw + (size_t)gwave * ROW_ELEMS);
#pragma unroll
        for (int c = 0; c < 8; ++c) A[c] = q0[c * 64 + lane];
#pragma unroll
        for (int c = 0; c < 8; ++c) B[c] = q0[(c + 8) * 64 + lane];
    }

#pragma unroll
    for (int r = 0; r < RPW; ++r) {
        const int row = gwave + NWAVES * r;
        const uint4* qn = reinterpret_cast<const uint4*>(
            qw + (size_t)(row + NWAVES) * ROW_ELEMS);  // next row (guarded below)

        float acc = 0.f;

        // consume first half-row (chunks 0..7): 1 ds_read_b32 + 1 fdot2 / code
#pragma unroll
        for (int c = 0; c < 8; ++c) {
            const uint32_t dws[4] = {A[c].x, A[c].y, A[c].z, A[c].w};
#pragma unroll
            for (int k = 0; k < 4; ++k) {
                const uint32_t idx = dws[k] & 0xffu;
                acc = dot2acc(xp[c * 4 + k],
                              __builtin_bit_cast(half2_t, pairlut[wave][r][idx]),
                              acc);
            }
        }
        // refill A from next row; its latency hides under the B half-row below
        if (r + 1 < RPW) {
#pragma unroll
            for (int c = 0; c < 8; ++c) A[c] = qn[c * 64 + lane];
        }
        // consume second half-row (chunks 8..15)
#pragma unroll
        for (int c = 8; c < 16; ++c) {
            const uint32_t dws[4] = {B[c - 8].x, B[c - 8].y, B[c - 8].z, B[c - 8].w};
#pragma unroll
            for (int k = 0; k < 4; ++k) {
                const uint32_t idx = dws[k] & 0xffu;
                acc = dot2acc(xp[c * 4 + k],
                              __builtin_bit_cast(half2_t, pairlut[wave][r][idx]),
                              acc);
            }
        }
        if (r + 1 < RPW) {
#pragma unroll
            for (int c = 0; c < 8; ++c) B[c] = qn[(c + 8) * 64 + lane];
        }

        // ---- Wave reduction + epilogue.
#pragma unroll
        for (int off = 32; off > 0; off >>= 1)
            acc += __shfl_xor(acc, off, 64);
        if (lane == 0) out[row] = acc + biasv[r];
    }
}

extern "C" void kernel_launch(void* const* d_in, const int* in_sizes, int n_in,
                              void* d_out, int out_size, void* d_ws, size_t ws_size,
                              hipStream_t stream) {
    const float* x    = (const float*)d_in[0];
    const int*   qw   = (const int*)d_in[1];
    const float* kmv  = (const float*)d_in[2];
    const float* bias = (const float*)d_in[3];
    float*       out  = (float*)d_out;

    hipLaunchKernelGGL(q4lut_matvec, dim3(NBLOCKS), dim3(256), 0, stream,
                       x, qw, kmv, bias, out);
}